// Round 5
// baseline (218.296 us; speedup 1.0000x reference)
//
#include <hip/hip_runtime.h>
#include <stdint.h>

// CDSSM: conv1(128ch,k3) -> tanh -> conv2(128ch,k3) -> tanh -> max_t -> proj -> tanh
//        then dots(q·pos, q·negs) -> gamma -> softmax.  B=64,T=2048,D=K=K2=128,L=64,J=2.
// R5: occupancy attack. R4 was latency-bound at 1 block/CU (LDS 161KB, barriers drain
//     the CU). Cut LDS to 64000B: (1) W1 all-taps global fragment-major (like W2),
//     (2) single X buffer (dbuf was unnecessary: barrier(1) already orders X-reads
//     before the staging write). -> 2 blocks/CU, 4 waves/SIMD, barrier drains overlap.

typedef __bf16 bf16x8 __attribute__((ext_vector_type(8)));
typedef __bf16 bf16x4 __attribute__((ext_vector_type(4)));
typedef float f32x16 __attribute__((ext_vector_type(16)));
typedef unsigned short u16x8 __attribute__((ext_vector_type(8)));

__device__ __forceinline__ unsigned short f2bf(float f) {
  unsigned u = __builtin_bit_cast(unsigned, f);
  u = u + 0x7FFFu + ((u >> 16) & 1u);   // RTNE
  return (unsigned short)(u >> 16);
}

__device__ __forceinline__ float fast_tanh(float x) {
  x = fminf(10.0f, fmaxf(-10.0f, x));
  float t = __builtin_amdgcn_exp2f(x * -2.8853900817779268f);   // e^{-2x}
  return (1.0f - t) * __builtin_amdgcn_rcpf(1.0f + t);
}

// ---------------- prep: fp32 [k][d][f] -> bf16 fragment-major [br][f][kk][row][hi][j] ----------------
__global__ void prep_kernel(const float* __restrict__ qw1, const float* __restrict__ qw2,
                            const float* __restrict__ dw1, const float* __restrict__ dw2,
                            unsigned short* __restrict__ W1f, unsigned short* __restrict__ W2f) {
  int gid = blockIdx.x * 256 + threadIdx.x;          // 768*256 = 196608 exact
  int which = gid >= 98304;                          // 0: W1f, 1: W2f
  int e = which ? gid - 98304 : gid;
  int br = e / 49152; int r = e % 49152;
  int f = r / 16384; int r2 = r & 16383;
  int kk = r2 >> 11; int row = (r2 >> 4) & 127; int hi = (r2 >> 3) & 1; int j = r2 & 7;
  int c = kk * 16 + hi * 8 + j;
  const float* src = which ? (br ? dw2 : qw2) : (br ? dw1 : qw1);
  (which ? W2f : W1f)[e] = f2bf(src[row * 384 + c * 3 + f]);
}

// ---------------- main fused conv kernel ----------------
// LDS (dynamic, 64000 B -> 2 blocks/CU):
//  XS  0     : bf16 [124 slot][128 d], swizzled  (31744)
//  H1S 31744 : bf16 [122 slot][128 k], swizzled  (31232)
//  B1  62976 / B2 63488 : float[128] biases      (1024)
#define XS_OFF  0
#define H1S_OFF 31744
#define B1_OFF  62976
#define B2_OFF  63488
#define LDS_TOTAL 64000
#define WIN 124        // X slots per window
#define STRIDE 120     // fresh outputs per iter
#define NIT 9          // ceil(1022/120)

__global__ __launch_bounds__(512)
__attribute__((amdgpu_waves_per_eu(4)))
void cdssm_main(
    const float* __restrict__ q, const float* __restrict__ pos, const float* __restrict__ negs,
    const unsigned short* __restrict__ W1f, const unsigned short* __restrict__ W2f,
    const float* __restrict__ qb1, const float* __restrict__ qb2,
    const float* __restrict__ db1, const float* __restrict__ db2,
    float* __restrict__ hpart) {
  extern __shared__ char lds[];
  const int tid = threadIdx.x;
  const int bid = blockIdx.x;
  const int seq = bid >> 1;
  const int half = bid & 1;
  const int branch = (seq < 64) ? 0 : 1;
  const float* xptr = (seq < 64) ? (q + (size_t)seq * 2048 * 128)
                    : (seq < 128) ? (pos + (size_t)(seq - 64) * 2048 * 128)
                                  : (negs + (size_t)(seq - 128) * 2048 * 128);
  const float* b1g = branch ? db1 : qb1;
  const float* b2g = branch ? db2 : qb2;
  const int lo = half * 1022;
  const int hi = lo + 1022;   // 2*1022 = 2044 = T-4 outputs total

  // ---- stage biases ----
  if (tid < 128) ((float*)(lds + B1_OFF))[tid] = b1g[tid];
  else if (tid < 256) ((float*)(lds + B2_OFF))[tid - 128] = b2g[tid - 128];

  const int lane = tid & 63;
  const int w = tid >> 6;            // 8 waves
  const int lrow = lane & 31;
  const int hi5 = lane >> 5;         // k-group
  const int r0 = (w & 3) * 32;       // output-row tile
  const int cbase = (w >> 2) * 64;   // 2 col tiles of 32
  const int row1 = r0 + lrow;

  const int hi16 = hi5 * 16;         // byte offset of k-group

  // fragment-major weight bases (per-lane part folded in); +f*16384 +kk*2048 per use
  const unsigned short* w1fb = W1f + (size_t)branch * 49152 + row1 * 16 + hi5 * 8;
  const unsigned short* w2fb = W2f + (size_t)branch * 49152 + row1 * 16 + hi5 * 8;

  float vmax[16];
#pragma unroll
  for (int r = 0; r < 16; ++r) vmax[r] = -2.0f;

  // ---- prologue: stage X window 0 ----
  for (int c2 = tid; c2 < WIN * 16; c2 += 512) {
    int slot = c2 >> 4;
    int d0 = (c2 & 15) * 8;
    int t = lo + slot; if (t > 2047) t = 2047;
    const float* src = xptr + ((size_t)t * 128 + d0);
    float4 v0 = *(const float4*)src;
    float4 v1 = *(const float4*)(src + 4);
    bf16x8 o;
    o[0] = (__bf16)v0.x; o[1] = (__bf16)v0.y; o[2] = (__bf16)v0.z; o[3] = (__bf16)v0.w;
    o[4] = (__bf16)v1.x; o[5] = (__bf16)v1.y; o[6] = (__bf16)v1.z; o[7] = (__bf16)v1.w;
    *(bf16x8*)(lds + XS_OFF + slot * 256 + ((d0 * 2) ^ ((slot & 15) << 4))) = o;
  }
  __syncthreads();   // X(0) + biases ready

  for (int it = 0; it < NIT; ++it) {
    const int base = lo + it * STRIDE;

    // ---- layer 1: h1[k, s] = tanh(b1 + sum_f sum_d W1[k,d,f] * X[base+s+f, d]) ----
    {
      f32x16 acc0, acc1;
#pragma unroll
      for (int r = 0; r < 16; ++r) { acc0[r] = 0.f; acc1[r] = 0.f; }
#pragma unroll 1
      for (int f = 0; f < 3; ++f) {
        bf16x8 a1[8];
#pragma unroll
        for (int kk = 0; kk < 8; ++kk)
          a1[kk] = __builtin_bit_cast(bf16x8, *(const u16x8*)(w1fb + f * 16384 + kk * 2048));
        int s0v = cbase + lrow + f;       if (s0v > WIN - 1) s0v = WIN - 1;
        int s1v = cbase + 32 + lrow + f;  if (s1v > WIN - 1) s1v = WIN - 1;
        int b0b = XS_OFF + s0v * 256, b0z = (s0v & 15) << 4;
        int b1b = XS_OFF + s1v * 256, b1z = (s1v & 15) << 4;
#pragma unroll
        for (int kk = 0; kk < 8; ++kk) {
          bf16x8 b0 = __builtin_bit_cast(bf16x8,
              *(const u16x8*)(lds + b0b + ((kk * 32 + hi16) ^ b0z)));
          acc0 = __builtin_amdgcn_mfma_f32_32x32x16_bf16(a1[kk], b0, acc0, 0, 0, 0);
          bf16x8 b1v = __builtin_bit_cast(bf16x8,
              *(const u16x8*)(lds + b1b + ((kk * 32 + hi16) ^ b1z)));
          acc1 = __builtin_amdgcn_mfma_f32_32x32x16_bf16(a1[kk], b1v, acc1, 0, 0, 0);
        }
      }
      // epilogue: h1 slots 0..121
#pragma unroll
      for (int cf = 0; cf < 2; ++cf) {
        const f32x16 acc = cf ? acc1 : acc0;
        int s = cbase + cf * 32 + lrow;       // C layout: col = lane&31
        if (s < 122) {
          int wb = H1S_OFF + s * 256;
          int wz = (s & 15) << 4;
#pragma unroll
          for (int qd = 0; qd < 4; ++qd) {
            int k0 = r0 + qd * 8 + hi5 * 4;   // C rows: (reg&3)+8*(reg>>2)+4*hi
            float4 bq = *(const float4*)(lds + B1_OFF + k0 * 4);
            bf16x4 hv;
            hv[0] = (__bf16)fast_tanh(acc[qd * 4 + 0] + bq.x);
            hv[1] = (__bf16)fast_tanh(acc[qd * 4 + 1] + bq.y);
            hv[2] = (__bf16)fast_tanh(acc[qd * 4 + 2] + bq.z);
            hv[3] = (__bf16)fast_tanh(acc[qd * 4 + 3] + bq.w);
            *(bf16x4*)(lds + wb + ((k0 * 2) ^ wz)) = hv;
          }
        }
      }
    }
    __syncthreads();   // (1) h1 ready; all X(it) reads done

    // ---- issue next-window global loads (latency hides under L2 MFMA) ----
    float4 va[8];
    const bool has4 = tid < (WIN * 16 - 1536);   // 1984 chunks
    if (it < NIT - 1) {
      const int basen = base + STRIDE;
#pragma unroll
      for (int u = 0; u < 3; ++u) {
        int c2 = tid + 512 * u;
        int slot = c2 >> 4;
        int d0 = (c2 & 15) * 8;
        int t = basen + slot; if (t > 2047) t = 2047;
        const float* src = xptr + ((size_t)t * 128 + d0);
        va[2 * u]     = *(const float4*)src;
        va[2 * u + 1] = *(const float4*)(src + 4);
      }
      if (has4) {
        int c2 = tid + 1536;
        int slot = c2 >> 4;
        int d0 = (c2 & 15) * 8;
        int t = basen + slot; if (t > 2047) t = 2047;
        const float* src = xptr + ((size_t)t * 128 + d0);
        va[6] = *(const float4*)src;
        va[7] = *(const float4*)(src + 4);
      }
    }

    // ---- layer 2: y2[k2, s2] = tanh(b2 + sum_f sum_c W2[k2,c,f] * h1[c, s2+f]) ----
    {
      f32x16 acc0, acc1;
#pragma unroll
      for (int r = 0; r < 16; ++r) { acc0[r] = 0.f; acc1[r] = 0.f; }
#pragma unroll 1
      for (int f = 0; f < 3; ++f) {
        bf16x8 a2[8];
#pragma unroll
        for (int kk = 0; kk < 8; ++kk)
          a2[kk] = __builtin_bit_cast(bf16x8, *(const u16x8*)(w2fb + f * 16384 + kk * 2048));
        int s0v = cbase + lrow + f;       if (s0v > 121) s0v = 121;
        int s1v = cbase + 32 + lrow + f;  if (s1v > 121) s1v = 121;
        int hb0 = H1S_OFF + s0v * 256, hz0 = (s0v & 15) << 4;
        int hb1 = H1S_OFF + s1v * 256, hz1 = (s1v & 15) << 4;
#pragma unroll
        for (int kk = 0; kk < 8; ++kk) {
          bf16x8 b0 = __builtin_bit_cast(bf16x8,
              *(const u16x8*)(lds + hb0 + ((kk * 32 + hi16) ^ hz0)));
          acc0 = __builtin_amdgcn_mfma_f32_32x32x16_bf16(a2[kk], b0, acc0, 0, 0, 0);
          bf16x8 b1v = __builtin_bit_cast(bf16x8,
              *(const u16x8*)(lds + hb1 + ((kk * 32 + hi16) ^ hz1)));
          acc1 = __builtin_amdgcn_mfma_f32_32x32x16_bf16(a2[kk], b1v, acc1, 0, 0, 0);
        }
      }

      // ---- convert + write next X window (X reads finished at barrier(1)) ----
      if (it < NIT - 1) {
#pragma unroll
        for (int u = 0; u < 3; ++u) {
          int c2 = tid + 512 * u;
          int slot = c2 >> 4;
          int d0 = (c2 & 15) * 8;
          const float* f0 = (const float*)&va[2 * u];
          bf16x8 o;
#pragma unroll
          for (int j = 0; j < 8; ++j) o[j] = (__bf16)f0[j];
          *(bf16x8*)(lds + XS_OFF + slot * 256 + ((d0 * 2) ^ ((slot & 15) << 4))) = o;
        }
        if (has4) {
          int c2 = tid + 1536;
          int slot = c2 >> 4;
          int d0 = (c2 & 15) * 8;
          const float* f0 = (const float*)&va[6];
          bf16x8 o;
#pragma unroll
          for (int j = 0; j < 8; ++j) o[j] = (__bf16)f0[j];
          *(bf16x8*)(lds + XS_OFF + slot * 256 + ((d0 * 2) ^ ((slot & 15) << 4))) = o;
        }
      }

      // epilogue: running max over valid outputs
#pragma unroll
      for (int cf = 0; cf < 2; ++cf) {
        const f32x16 acc = cf ? acc1 : acc0;
        int s2 = cbase + cf * 32 + lrow;
        bool valid = (s2 < STRIDE) && (base + s2 < hi);
#pragma unroll
        for (int qd = 0; qd < 4; ++qd) {
          int k0 = r0 + qd * 8 + hi5 * 4;
          float4 bq = *(const float4*)(lds + B2_OFF + k0 * 4);
#pragma unroll
          for (int jj = 0; jj < 4; ++jj) {
            float v = fast_tanh(acc[qd * 4 + jj] + ((const float*)&bq)[jj]);
            v = valid ? v : -2.0f;
            vmax[qd * 4 + jj] = fmaxf(vmax[qd * 4 + jj], v);
          }
        }
      }
    }
    __syncthreads();   // (2) X(it+1) ready; h1 free for overwrite
  }

  // reduce vmax across the 32 columns (each half-wave holds its own 16 rows)
#pragma unroll
  for (int r = 0; r < 16; ++r) {
    float v = vmax[r];
    v = fmaxf(v, __shfl_xor(v, 1, 64));
    v = fmaxf(v, __shfl_xor(v, 2, 64));
    v = fmaxf(v, __shfl_xor(v, 4, 64));
    v = fmaxf(v, __shfl_xor(v, 8, 64));
    v = fmaxf(v, __shfl_xor(v, 16, 64));
    vmax[r] = v;
  }
  float* hbuf = (float*)(lds + XS_OFF);   // reuse X region
  if (w < 4 && lrow == 0) {
#pragma unroll
    for (int r = 0; r < 16; ++r)
      hbuf[r0 + (r & 3) + 8 * (r >> 2) + 4 * hi5] = vmax[r];
  }
  __syncthreads();
  if (w >= 4 && lrow == 0) {
#pragma unroll
    for (int r = 0; r < 16; ++r) {
      int row = r0 + (r & 3) + 8 * (r >> 2) + 4 * hi5;
      hbuf[row] = fmaxf(hbuf[row], vmax[r]);
    }
  }
  __syncthreads();
  if (tid < 128) hpart[(size_t)bid * 128 + tid] = hbuf[tid];
}

// ---------------- k2: combine halves, project, tanh ----------------
__global__ void k2_proj(const float* __restrict__ hpart,
                        const float* __restrict__ qsw, const float* __restrict__ qsb,
                        const float* __restrict__ dsw, const float* __restrict__ dsb,
                        float* __restrict__ s_out) {
  int seq = blockIdx.x;        // 256
  int l = threadIdx.x;         // 64
  const float* sw = (seq < 64) ? qsw : dsw;
  const float* sb = (seq < 64) ? qsb : dsb;
  const float* h0 = hpart + (size_t)(2 * seq) * 128;
  const float* h1 = h0 + 128;
  float acc = sb[l];
  for (int k = 0; k < 128; ++k)
    acc += fmaxf(h0[k], h1[k]) * sw[l * 128 + k];
  s_out[(size_t)seq * 64 + l] = fast_tanh(acc);
}

// ---------------- k3: dots, gamma, softmax ----------------
__global__ void k3_softmax(const float* __restrict__ s_out,
                           const float* __restrict__ gw, const float* __restrict__ gb,
                           float* __restrict__ out) {
  int b = threadIdx.x;   // 64
  const float* qs = s_out + (size_t)b * 64;
  const float* ps = s_out + (size_t)(64 + b) * 64;
  const float* n0 = s_out + (size_t)(128 + b) * 64;
  const float* n1 = s_out + (size_t)(192 + b) * 64;
  float d0 = 0.f, d1 = 0.f, d2 = 0.f;
  for (int l = 0; l < 64; ++l) {
    float v = qs[l];
    d0 += v * ps[l];
    d1 += v * n0[l];
    d2 += v * n1[l];
  }
  float g = gw[0], bb = gb[0];
  d0 = g * d0 + bb; d1 = g * d1 + bb; d2 = g * d2 + bb;
  float m = fmaxf(d0, fmaxf(d1, d2));
  float e0 = expf(d0 - m), e1 = expf(d1 - m), e2 = expf(d2 - m);
  float inv = 1.0f / (e0 + e1 + e2);
  out[b * 3 + 0] = e0 * inv;
  out[b * 3 + 1] = e1 * inv;
  out[b * 3 + 2] = e2 * inv;
}

extern "C" void kernel_launch(void* const* d_in, const int* in_sizes, int n_in,
                              void* d_out, int out_size, void* d_ws, size_t ws_size,
                              hipStream_t stream) {
  const float* q    = (const float*)d_in[0];
  const float* pos  = (const float*)d_in[1];
  const float* negs = (const float*)d_in[2];
  const float* qw1  = (const float*)d_in[3];
  const float* qb1  = (const float*)d_in[4];
  const float* qw2  = (const float*)d_in[5];
  const float* qb2  = (const float*)d_in[6];
  const float* qsw  = (const float*)d_in[7];
  const float* qsb  = (const float*)d_in[8];
  const float* dw1  = (const float*)d_in[9];
  const float* db1  = (const float*)d_in[10];
  const float* dw2  = (const float*)d_in[11];
  const float* db2  = (const float*)d_in[12];
  const float* dsw  = (const float*)d_in[13];
  const float* dsb  = (const float*)d_in[14];
  const float* gw   = (const float*)d_in[15];
  const float* gb   = (const float*)d_in[16];
  float* out = (float*)d_out;

  char* ws = (char*)d_ws;
  unsigned short* W1f = (unsigned short*)(ws);             // 98304 elems = 196608 B
  unsigned short* W2f = (unsigned short*)(ws + 196608);    // 98304 elems = 196608 B
  float* hpart        = (float*)(ws + 393216);             // 512*128*4 = 262144 B
  float* s_out        = (float*)(ws + 655360);             // 256*64*4  = 65536 B

  hipFuncSetAttribute((const void*)cdssm_main,
                      hipFuncAttributeMaxDynamicSharedMemorySize, LDS_TOTAL);

  prep_kernel<<<768, 256, 0, stream>>>(qw1, qw2, dw1, dw2, W1f, W2f);
  cdssm_main<<<512, 512, LDS_TOTAL, stream>>>(q, pos, negs, W1f, W2f,
                                              qb1, qb2, db1, db2, hpart);
  k2_proj<<<256, 64, 0, stream>>>(hpart, qsw, qsb, dsw, dsb, s_out);
  k3_softmax<<<1, 64, 0, stream>>>(s_out, gw, gb, out);
}

// Round 6
// 213.122 us; speedup vs baseline: 1.0243x; 1.0243x over previous
//
#include <hip/hip_runtime.h>
#include <stdint.h>

// CDSSM: conv1(128ch,k3) -> tanh -> conv2(128ch,k3) -> tanh -> max_t -> proj -> tanh
//        then dots(q·pos, q·negs) -> gamma -> softmax.  B=64,T=2048,D=K=K2=128,L=64,J=2.
// R6: R5 structure (64KB LDS -> 2 blocks/CU) but waves_per_eu(4,4) EXACT pin:
//     R5's waves_per_eu(4) [min-only] let the allocator squeeze to 64 VGPR chasing
//     8 waves/EU -> 45MB spills. Pin 4 waves/EU -> 128-VGPR cap, R4-proven fit.

typedef __bf16 bf16x8 __attribute__((ext_vector_type(8)));
typedef __bf16 bf16x4 __attribute__((ext_vector_type(4)));
typedef float f32x16 __attribute__((ext_vector_type(16)));
typedef unsigned short u16x8 __attribute__((ext_vector_type(8)));

__device__ __forceinline__ unsigned short f2bf(float f) {
  unsigned u = __builtin_bit_cast(unsigned, f);
  u = u + 0x7FFFu + ((u >> 16) & 1u);   // RTNE
  return (unsigned short)(u >> 16);
}

__device__ __forceinline__ float fast_tanh(float x) {
  x = fminf(10.0f, fmaxf(-10.0f, x));
  float t = __builtin_amdgcn_exp2f(x * -2.8853900817779268f);   // e^{-2x}
  return (1.0f - t) * __builtin_amdgcn_rcpf(1.0f + t);
}

// ---------------- prep: fp32 [k][d][f] -> bf16 fragment-major [br][f][kk][row][hi][j] ----------------
__global__ void prep_kernel(const float* __restrict__ qw1, const float* __restrict__ qw2,
                            const float* __restrict__ dw1, const float* __restrict__ dw2,
                            unsigned short* __restrict__ W1f, unsigned short* __restrict__ W2f) {
  int gid = blockIdx.x * 256 + threadIdx.x;          // 768*256 = 196608 exact
  int which = gid >= 98304;                          // 0: W1f, 1: W2f
  int e = which ? gid - 98304 : gid;
  int br = e / 49152; int r = e % 49152;
  int f = r / 16384; int r2 = r & 16383;
  int kk = r2 >> 11; int row = (r2 >> 4) & 127; int hi = (r2 >> 3) & 1; int j = r2 & 7;
  int c = kk * 16 + hi * 8 + j;
  const float* src = which ? (br ? dw2 : qw2) : (br ? dw1 : qw1);
  (which ? W2f : W1f)[e] = f2bf(src[row * 384 + c * 3 + f]);
}

// ---------------- main fused conv kernel ----------------
// LDS (dynamic, 64000 B -> 2 blocks/CU):
//  XS  0     : bf16 [124 slot][128 d], swizzled  (31744)
//  H1S 31744 : bf16 [122 slot][128 k], swizzled  (31232)
//  B1  62976 / B2 63488 : float[128] biases      (1024)
#define XS_OFF  0
#define H1S_OFF 31744
#define B1_OFF  62976
#define B2_OFF  63488
#define LDS_TOTAL 64000
#define WIN 124        // X slots per window
#define STRIDE 120     // fresh outputs per iter
#define NIT 9          // ceil(1022/120)

__global__ __launch_bounds__(512)
__attribute__((amdgpu_waves_per_eu(4, 4)))
void cdssm_main(
    const float* __restrict__ q, const float* __restrict__ pos, const float* __restrict__ negs,
    const unsigned short* __restrict__ W1f, const unsigned short* __restrict__ W2f,
    const float* __restrict__ qb1, const float* __restrict__ qb2,
    const float* __restrict__ db1, const float* __restrict__ db2,
    float* __restrict__ hpart) {
  extern __shared__ char lds[];
  const int tid = threadIdx.x;
  const int bid = blockIdx.x;
  const int seq = bid >> 1;
  const int half = bid & 1;
  const int branch = (seq < 64) ? 0 : 1;
  const float* xptr = (seq < 64) ? (q + (size_t)seq * 2048 * 128)
                    : (seq < 128) ? (pos + (size_t)(seq - 64) * 2048 * 128)
                                  : (negs + (size_t)(seq - 128) * 2048 * 128);
  const float* b1g = branch ? db1 : qb1;
  const float* b2g = branch ? db2 : qb2;
  const int lo = half * 1022;
  const int hi = lo + 1022;   // 2*1022 = 2044 = T-4 outputs total

  // ---- stage biases ----
  if (tid < 128) ((float*)(lds + B1_OFF))[tid] = b1g[tid];
  else if (tid < 256) ((float*)(lds + B2_OFF))[tid - 128] = b2g[tid - 128];

  const int lane = tid & 63;
  const int w = tid >> 6;            // 8 waves
  const int lrow = lane & 31;
  const int hi5 = lane >> 5;         // k-group
  const int r0 = (w & 3) * 32;       // output-row tile
  const int cbase = (w >> 2) * 64;   // 2 col tiles of 32
  const int row1 = r0 + lrow;

  const int hi16 = hi5 * 16;         // byte offset of k-group

  // fragment-major weight bases (per-lane part folded in); +f*16384 +kk*2048 per use
  const unsigned short* w1fb = W1f + (size_t)branch * 49152 + row1 * 16 + hi5 * 8;
  const unsigned short* w2fb = W2f + (size_t)branch * 49152 + row1 * 16 + hi5 * 8;

  float vmax[16];
#pragma unroll
  for (int r = 0; r < 16; ++r) vmax[r] = -2.0f;

  // ---- prologue: stage X window 0 ----
  for (int c2 = tid; c2 < WIN * 16; c2 += 512) {
    int slot = c2 >> 4;
    int d0 = (c2 & 15) * 8;
    int t = lo + slot; if (t > 2047) t = 2047;
    const float* src = xptr + ((size_t)t * 128 + d0);
    float4 v0 = *(const float4*)src;
    float4 v1 = *(const float4*)(src + 4);
    bf16x8 o;
    o[0] = (__bf16)v0.x; o[1] = (__bf16)v0.y; o[2] = (__bf16)v0.z; o[3] = (__bf16)v0.w;
    o[4] = (__bf16)v1.x; o[5] = (__bf16)v1.y; o[6] = (__bf16)v1.z; o[7] = (__bf16)v1.w;
    *(bf16x8*)(lds + XS_OFF + slot * 256 + ((d0 * 2) ^ ((slot & 15) << 4))) = o;
  }
  __syncthreads();   // X(0) + biases ready

  for (int it = 0; it < NIT; ++it) {
    const int base = lo + it * STRIDE;

    // ---- layer 1: h1[k, s] = tanh(b1 + sum_f sum_d W1[k,d,f] * X[base+s+f, d]) ----
    {
      f32x16 acc0, acc1;
#pragma unroll
      for (int r = 0; r < 16; ++r) { acc0[r] = 0.f; acc1[r] = 0.f; }
#pragma unroll 1
      for (int f = 0; f < 3; ++f) {
        bf16x8 a1[8];
#pragma unroll
        for (int kk = 0; kk < 8; ++kk)
          a1[kk] = __builtin_bit_cast(bf16x8, *(const u16x8*)(w1fb + f * 16384 + kk * 2048));
        int s0v = cbase + lrow + f;       if (s0v > WIN - 1) s0v = WIN - 1;
        int s1v = cbase + 32 + lrow + f;  if (s1v > WIN - 1) s1v = WIN - 1;
        int b0b = XS_OFF + s0v * 256, b0z = (s0v & 15) << 4;
        int b1b = XS_OFF + s1v * 256, b1z = (s1v & 15) << 4;
#pragma unroll
        for (int kk = 0; kk < 8; ++kk) {
          bf16x8 b0 = __builtin_bit_cast(bf16x8,
              *(const u16x8*)(lds + b0b + ((kk * 32 + hi16) ^ b0z)));
          acc0 = __builtin_amdgcn_mfma_f32_32x32x16_bf16(a1[kk], b0, acc0, 0, 0, 0);
          bf16x8 b1v = __builtin_bit_cast(bf16x8,
              *(const u16x8*)(lds + b1b + ((kk * 32 + hi16) ^ b1z)));
          acc1 = __builtin_amdgcn_mfma_f32_32x32x16_bf16(a1[kk], b1v, acc1, 0, 0, 0);
        }
      }
      // epilogue: h1 slots 0..121
#pragma unroll
      for (int cf = 0; cf < 2; ++cf) {
        const f32x16 acc = cf ? acc1 : acc0;
        int s = cbase + cf * 32 + lrow;       // C layout: col = lane&31
        if (s < 122) {
          int wb = H1S_OFF + s * 256;
          int wz = (s & 15) << 4;
#pragma unroll
          for (int qd = 0; qd < 4; ++qd) {
            int k0 = r0 + qd * 8 + hi5 * 4;   // C rows: (reg&3)+8*(reg>>2)+4*hi
            float4 bq = *(const float4*)(lds + B1_OFF + k0 * 4);
            bf16x4 hv;
            hv[0] = (__bf16)fast_tanh(acc[qd * 4 + 0] + bq.x);
            hv[1] = (__bf16)fast_tanh(acc[qd * 4 + 1] + bq.y);
            hv[2] = (__bf16)fast_tanh(acc[qd * 4 + 2] + bq.z);
            hv[3] = (__bf16)fast_tanh(acc[qd * 4 + 3] + bq.w);
            *(bf16x4*)(lds + wb + ((k0 * 2) ^ wz)) = hv;
          }
        }
      }
    }
    __syncthreads();   // (1) h1 ready; all X(it) reads done

    // ---- issue next-window global loads (latency hides under L2 MFMA) ----
    float4 va[8];
    const bool has4 = tid < (WIN * 16 - 1536);   // 1984 chunks
    if (it < NIT - 1) {
      const int basen = base + STRIDE;
#pragma unroll
      for (int u = 0; u < 3; ++u) {
        int c2 = tid + 512 * u;
        int slot = c2 >> 4;
        int d0 = (c2 & 15) * 8;
        int t = basen + slot; if (t > 2047) t = 2047;
        const float* src = xptr + ((size_t)t * 128 + d0);
        va[2 * u]     = *(const float4*)src;
        va[2 * u + 1] = *(const float4*)(src + 4);
      }
      if (has4) {
        int c2 = tid + 1536;
        int slot = c2 >> 4;
        int d0 = (c2 & 15) * 8;
        int t = basen + slot; if (t > 2047) t = 2047;
        const float* src = xptr + ((size_t)t * 128 + d0);
        va[6] = *(const float4*)src;
        va[7] = *(const float4*)(src + 4);
      }
    }

    // ---- layer 2: y2[k2, s2] = tanh(b2 + sum_f sum_c W2[k2,c,f] * h1[c, s2+f]) ----
    {
      f32x16 acc0, acc1;
#pragma unroll
      for (int r = 0; r < 16; ++r) { acc0[r] = 0.f; acc1[r] = 0.f; }
#pragma unroll 1
      for (int f = 0; f < 3; ++f) {
        bf16x8 a2[8];
#pragma unroll
        for (int kk = 0; kk < 8; ++kk)
          a2[kk] = __builtin_bit_cast(bf16x8, *(const u16x8*)(w2fb + f * 16384 + kk * 2048));
        int s0v = cbase + lrow + f;       if (s0v > 121) s0v = 121;
        int s1v = cbase + 32 + lrow + f;  if (s1v > 121) s1v = 121;
        int hb0 = H1S_OFF + s0v * 256, hz0 = (s0v & 15) << 4;
        int hb1 = H1S_OFF + s1v * 256, hz1 = (s1v & 15) << 4;
#pragma unroll
        for (int kk = 0; kk < 8; ++kk) {
          bf16x8 b0 = __builtin_bit_cast(bf16x8,
              *(const u16x8*)(lds + hb0 + ((kk * 32 + hi16) ^ hz0)));
          acc0 = __builtin_amdgcn_mfma_f32_32x32x16_bf16(a2[kk], b0, acc0, 0, 0, 0);
          bf16x8 b1v = __builtin_bit_cast(bf16x8,
              *(const u16x8*)(lds + hb1 + ((kk * 32 + hi16) ^ hz1)));
          acc1 = __builtin_amdgcn_mfma_f32_32x32x16_bf16(a2[kk], b1v, acc1, 0, 0, 0);
        }
      }

      // ---- convert + write next X window (X reads finished at barrier(1)) ----
      if (it < NIT - 1) {
#pragma unroll
        for (int u = 0; u < 3; ++u) {
          int c2 = tid + 512 * u;
          int slot = c2 >> 4;
          int d0 = (c2 & 15) * 8;
          const float* f0 = (const float*)&va[2 * u];
          bf16x8 o;
#pragma unroll
          for (int j = 0; j < 8; ++j) o[j] = (__bf16)f0[j];
          *(bf16x8*)(lds + XS_OFF + slot * 256 + ((d0 * 2) ^ ((slot & 15) << 4))) = o;
        }
        if (has4) {
          int c2 = tid + 1536;
          int slot = c2 >> 4;
          int d0 = (c2 & 15) * 8;
          const float* f0 = (const float*)&va[6];
          bf16x8 o;
#pragma unroll
          for (int j = 0; j < 8; ++j) o[j] = (__bf16)f0[j];
          *(bf16x8*)(lds + XS_OFF + slot * 256 + ((d0 * 2) ^ ((slot & 15) << 4))) = o;
        }
      }

      // epilogue: running max over valid outputs
#pragma unroll
      for (int cf = 0; cf < 2; ++cf) {
        const f32x16 acc = cf ? acc1 : acc0;
        int s2 = cbase + cf * 32 + lrow;
        bool valid = (s2 < STRIDE) && (base + s2 < hi);
#pragma unroll
        for (int qd = 0; qd < 4; ++qd) {
          int k0 = r0 + qd * 8 + hi5 * 4;
          float4 bq = *(const float4*)(lds + B2_OFF + k0 * 4);
#pragma unroll
          for (int jj = 0; jj < 4; ++jj) {
            float v = fast_tanh(acc[qd * 4 + jj] + ((const float*)&bq)[jj]);
            v = valid ? v : -2.0f;
            vmax[qd * 4 + jj] = fmaxf(vmax[qd * 4 + jj], v);
          }
        }
      }
    }
    __syncthreads();   // (2) X(it+1) ready; h1 free for overwrite
  }

  // reduce vmax across the 32 columns (each half-wave holds its own 16 rows)
#pragma unroll
  for (int r = 0; r < 16; ++r) {
    float v = vmax[r];
    v = fmaxf(v, __shfl_xor(v, 1, 64));
    v = fmaxf(v, __shfl_xor(v, 2, 64));
    v = fmaxf(v, __shfl_xor(v, 4, 64));
    v = fmaxf(v, __shfl_xor(v, 8, 64));
    v = fmaxf(v, __shfl_xor(v, 16, 64));
    vmax[r] = v;
  }
  float* hbuf = (float*)(lds + XS_OFF);   // reuse X region
  if (w < 4 && lrow == 0) {
#pragma unroll
    for (int r = 0; r < 16; ++r)
      hbuf[r0 + (r & 3) + 8 * (r >> 2) + 4 * hi5] = vmax[r];
  }
  __syncthreads();
  if (w >= 4 && lrow == 0) {
#pragma unroll
    for (int r = 0; r < 16; ++r) {
      int row = r0 + (r & 3) + 8 * (r >> 2) + 4 * hi5;
      hbuf[row] = fmaxf(hbuf[row], vmax[r]);
    }
  }
  __syncthreads();
  if (tid < 128) hpart[(size_t)bid * 128 + tid] = hbuf[tid];
}

// ---------------- k2: combine halves, project, tanh ----------------
__global__ void k2_proj(const float* __restrict__ hpart,
                        const float* __restrict__ qsw, const float* __restrict__ qsb,
                        const float* __restrict__ dsw, const float* __restrict__ dsb,
                        float* __restrict__ s_out) {
  int seq = blockIdx.x;        // 256
  int l = threadIdx.x;         // 64
  const float* sw = (seq < 64) ? qsw : dsw;
  const float* sb = (seq < 64) ? qsb : dsb;
  const float* h0 = hpart + (size_t)(2 * seq) * 128;
  const float* h1 = h0 + 128;
  float acc = sb[l];
  for (int k = 0; k < 128; ++k)
    acc += fmaxf(h0[k], h1[k]) * sw[l * 128 + k];
  s_out[(size_t)seq * 64 + l] = fast_tanh(acc);
}

// ---------------- k3: dots, gamma, softmax ----------------
__global__ void k3_softmax(const float* __restrict__ s_out,
                           const float* __restrict__ gw, const float* __restrict__ gb,
                           float* __restrict__ out) {
  int b = threadIdx.x;   // 64
  const float* qs = s_out + (size_t)b * 64;
  const float* ps = s_out + (size_t)(64 + b) * 64;
  const float* n0 = s_out + (size_t)(128 + b) * 64;
  const float* n1 = s_out + (size_t)(192 + b) * 64;
  float d0 = 0.f, d1 = 0.f, d2 = 0.f;
  for (int l = 0; l < 64; ++l) {
    float v = qs[l];
    d0 += v * ps[l];
    d1 += v * n0[l];
    d2 += v * n1[l];
  }
  float g = gw[0], bb = gb[0];
  d0 = g * d0 + bb; d1 = g * d1 + bb; d2 = g * d2 + bb;
  float m = fmaxf(d0, fmaxf(d1, d2));
  float e0 = expf(d0 - m), e1 = expf(d1 - m), e2 = expf(d2 - m);
  float inv = 1.0f / (e0 + e1 + e2);
  out[b * 3 + 0] = e0 * inv;
  out[b * 3 + 1] = e1 * inv;
  out[b * 3 + 2] = e2 * inv;
}

extern "C" void kernel_launch(void* const* d_in, const int* in_sizes, int n_in,
                              void* d_out, int out_size, void* d_ws, size_t ws_size,
                              hipStream_t stream) {
  const float* q    = (const float*)d_in[0];
  const float* pos  = (const float*)d_in[1];
  const float* negs = (const float*)d_in[2];
  const float* qw1  = (const float*)d_in[3];
  const float* qb1  = (const float*)d_in[4];
  const float* qw2  = (const float*)d_in[5];
  const float* qb2  = (const float*)d_in[6];
  const float* qsw  = (const float*)d_in[7];
  const float* qsb  = (const float*)d_in[8];
  const float* dw1  = (const float*)d_in[9];
  const float* db1  = (const float*)d_in[10];
  const float* dw2  = (const float*)d_in[11];
  const float* db2  = (const float*)d_in[12];
  const float* dsw  = (const float*)d_in[13];
  const float* dsb  = (const float*)d_in[14];
  const float* gw   = (const float*)d_in[15];
  const float* gb   = (const float*)d_in[16];
  float* out = (float*)d_out;

  char* ws = (char*)d_ws;
  unsigned short* W1f = (unsigned short*)(ws);             // 98304 elems = 196608 B
  unsigned short* W2f = (unsigned short*)(ws + 196608);    // 98304 elems = 196608 B
  float* hpart        = (float*)(ws + 393216);             // 512*128*4 = 262144 B
  float* s_out        = (float*)(ws + 655360);             // 256*64*4  = 65536 B

  hipFuncSetAttribute((const void*)cdssm_main,
                      hipFuncAttributeMaxDynamicSharedMemorySize, LDS_TOTAL);

  prep_kernel<<<768, 256, 0, stream>>>(qw1, qw2, dw1, dw2, W1f, W2f);
  cdssm_main<<<512, 512, LDS_TOTAL, stream>>>(q, pos, negs, W1f, W2f,
                                              qb1, qb2, db1, db2, hpart);
  k2_proj<<<256, 64, 0, stream>>>(hpart, qsw, qsb, dsw, dsb, s_out);
  k3_softmax<<<1, 64, 0, stream>>>(s_out, gw, gb, out);
}